// Round 1
// baseline (114.635 us; speedup 1.0000x reference)
//
#include <hip/hip_runtime.h>

// RaySamplerPDF: per-ray inverse-CDF sampling.
// One wave (64 lanes) per ray; each lane owns 2 bins and 2 samples (float2).
// CDF built via wave-shuffle inclusive scan, staged in LDS, binary search per sample.

constexpr int NUM_BINS    = 128;
constexpr int NUM_SAMPLES = 128;
constexpr float EPS_PAD   = 1e-5f;
constexpr int RPB         = 4;   // rays per block = waves per block

__global__ __launch_bounds__(256) void ray_sampler_kernel(
    const float* __restrict__ W,
    const float* __restrict__ U,
    const int*   __restrict__ stratp,
    float*       __restrict__ out)
{
    const int wave = threadIdx.x >> 6;
    const int lane = threadIdx.x & 63;
    const int ray  = blockIdx.x * RPB + wave;

    // CDF per ray: indices 0..128 used; pad stride to 132 floats.
    __shared__ float cdf_s[RPB][NUM_BINS + 4];

    // ---- load 2 weights per lane (coalesced float2) ----
    const size_t wbase = (size_t)ray * NUM_BINS;
    const float2 w2 = *reinterpret_cast<const float2*>(W + wbase + 2 * lane);
    const float pair = w2.x + w2.y;

    // ---- wave inclusive scan of pair sums ----
    float incl = pair;
    #pragma unroll
    for (int d = 1; d < 64; d <<= 1) {
        float n = __shfl_up(incl, d, 64);
        if (lane >= d) incl += n;
    }
    const float total   = __shfl(incl, 63, 64);
    const float padding = fmaxf(EPS_PAD - total, 0.0f);
    const float wsum    = total + padding;
    const float ppb     = padding * (1.0f / 128.0f);   // per-bin padding
    const float inv     = 1.0f / wsum;

    // cdf[2l+1], cdf[2l+2]: prefix of adjusted weights, normalized.
    const float pre = incl - pair;  // exclusive prefix of pairs
    cdf_s[wave][2 * lane + 1] = (pre + w2.x + (float)(2 * lane + 1) * ppb) * inv;
    cdf_s[wave][2 * lane + 2] = (incl        + (float)(2 * lane + 2) * ppb) * inv;
    if (lane == 0) cdf_s[wave][0] = 0.0f;
    __syncthreads();

    // ---- per-sample: us, binary search (upper bound), lerp ----
    const int strat = *stratp;
    const float2 u2 = *reinterpret_cast<const float2*>(U + (size_t)ray * NUM_SAMPLES + 2 * lane);
    const float invS = 1.0f / (float)NUM_SAMPLES;
    const int s0 = 2 * lane, s1 = 2 * lane + 1;
    const float us0 = strat ? ((float)s0 + u2.x) * invS : ((float)s0 + 0.5f) * invS;
    const float us1 = strat ? ((float)s1 + u2.y) * invS : ((float)s1 + 0.5f) * invS;

    const float* cdf = cdf_s[wave];
    auto sample_one = [&](float us) -> float {
        // first index in [0,129) with cdf[idx] > us  (searchsorted side='right')
        int lo = 0, hi = NUM_BINS + 1;
        #pragma unroll
        for (int it = 0; it < 8; ++it) {
            if (lo < hi) {
                int mid = (lo + hi) >> 1;
                if (cdf[mid] <= us) lo = mid + 1; else hi = mid;
            }
        }
        int below = lo - 1;
        below = below < 0 ? 0 : (below > NUM_BINS ? NUM_BINS : below);
        int above = lo > NUM_BINS ? NUM_BINS : lo;
        const float cb = cdf[below];
        const float ca = cdf[above];
        float denom = ca - cb;
        if (denom < 1e-5f) denom = 1.0f;
        const float t  = (us - cb) / denom;
        const float bb = (float)below * (1.0f / 128.0f);
        const float ba = (float)above * (1.0f / 128.0f);
        return bb + t * (ba - bb);
    };

    float2 o;
    o.x = sample_one(us0);
    o.y = sample_one(us1);
    *reinterpret_cast<float2*>(out + (size_t)ray * NUM_SAMPLES + 2 * lane) = o;
}

extern "C" void kernel_launch(void* const* d_in, const int* in_sizes, int n_in,
                              void* d_out, int out_size, void* d_ws, size_t ws_size,
                              hipStream_t stream) {
    const float* W     = (const float*)d_in[0];
    const float* U     = (const float*)d_in[1];
    const int*   strat = (const int*)d_in[2];
    float*       out   = (float*)d_out;

    const int num_rays = in_sizes[0] / NUM_BINS;   // 262144
    const int blocks   = num_rays / RPB;           // exact: 65536
    hipLaunchKernelGGL(ray_sampler_kernel, dim3(blocks), dim3(256), 0, stream,
                       W, U, strat, out);
}

// Round 3
// 69.799 us; speedup vs baseline: 1.6424x; 1.6424x over previous
//
#include <hip/hip_runtime.h>

// RaySamplerPDF: per-ray inverse-CDF sampling (NeRF fine sampling).
// One wave (64 lanes) per ray; lane owns 2 bins + 2 samples (float2).
// CDF via DPP wave scan -> LDS; branchless 7-step bit-descent search.

typedef float f32x2 __attribute__((ext_vector_type(2)));

constexpr int NUM_BINS    = 128;
constexpr int NUM_SAMPLES = 128;
constexpr float EPS_PAD   = 1e-5f;
constexpr float INV_S     = 1.0f / 128.0f;
constexpr int RPB         = 4;   // rays (waves) per 256-thread block

// x += dpp_moved(x); masked-out / out-of-bounds lanes add 0.
// DPP control and masks must be compile-time constants -> template params.
template <int CTRL, int ROW_MASK>
__device__ __forceinline__ float dpp_add(float x) {
    int s = __builtin_amdgcn_update_dpp(0, __float_as_int(x), CTRL, ROW_MASK, 0xf, true);
    return x + __int_as_float(s);
}

__global__ __launch_bounds__(256) void ray_sampler_kernel(
    const float* __restrict__ W,
    const float* __restrict__ U,
    const int*   __restrict__ stratp,
    float*       __restrict__ out)
{
    const int wave = threadIdx.x >> 6;
    const int lane = threadIdx.x & 63;
    const int ray  = blockIdx.x * RPB + wave;

    // per-wave private CDF slice; slots 1..128 used (slot 0 never read: cb init 0)
    __shared__ float cdf_s[RPB][NUM_BINS + 4];

    // ---- load 2 weights (coalesced 8B/lane) ----
    const f32x2 w2 = *reinterpret_cast<const f32x2*>(W + (size_t)ray * NUM_BINS + 2 * lane);
    const float pair = w2.x + w2.y;

    // ---- wave64 inclusive scan via DPP (rocPRIM sequence), no LDS ----
    float incl = pair;
    incl = dpp_add<0x111, 0xf>(incl);  // row_shr:1
    incl = dpp_add<0x112, 0xf>(incl);  // row_shr:2
    incl = dpp_add<0x114, 0xf>(incl);  // row_shr:4
    incl = dpp_add<0x118, 0xf>(incl);  // row_shr:8
    incl = dpp_add<0x142, 0xa>(incl);  // row_bcast:15 -> rows 1,3
    incl = dpp_add<0x143, 0xc>(incl);  // row_bcast:31 -> rows 2,3
    const float total = __shfl(incl, 63, 64);

    const float padding = fmaxf(EPS_PAD - total, 0.0f);
    const float ppb     = padding * INV_S;                       // per-bin padding
    const float inv     = __builtin_amdgcn_rcpf(total + padding);

    // cdf[2l+1], cdf[2l+2]
    const float pre = incl - pair;   // exclusive prefix of pair sums
    float* cw = cdf_s[wave];
    cw[2 * lane + 1] = (pre + w2.x + (float)(2 * lane + 1) * ppb) * inv;
    cw[2 * lane + 2] = (incl        + (float)(2 * lane + 2) * ppb) * inv;

    // wave-private LDS producer->consumer: drain LDS ops, no block barrier needed
    asm volatile("s_waitcnt lgkmcnt(0)" ::: "memory");

    // ---- uniforms ----
    const int strat = *stratp;
    const f32x2 u2 = *reinterpret_cast<const f32x2*>(U + (size_t)ray * NUM_SAMPLES + 2 * lane);
    const float uu0 = strat ? u2.x : 0.5f;
    const float uu1 = strat ? u2.y : 0.5f;
    const float us0 = ((float)(2 * lane)     + uu0) * INV_S;
    const float us1 = ((float)(2 * lane + 1) + uu1) * INV_S;

    // ---- branchless bit-descent: below = last j in [0,127] with cdf[j] <= us ----
    // (edge us >= cdf[128] resolves to t~1 in bin 127: error <= 1/128 << 2e-2 threshold)
    const float* cdf = cw;
    int a0 = 0, a1 = 0;
    float cb0 = 0.0f, cb1 = 0.0f;
    #pragma unroll
    for (int step = 64; step; step >>= 1) {
        const float c0 = cdf[a0 + step];
        const float c1 = cdf[a1 + step];
        if (c0 <= us0) { a0 += step; cb0 = c0; }
        if (c1 <= us1) { a1 += step; cb1 = c1; }
    }
    const float ca0 = cdf[a0 + 1];   // a <= 127 -> index <= 128, in bounds
    const float ca1 = cdf[a1 + 1];

    float d0 = ca0 - cb0;  d0 = (d0 < 1e-5f) ? 1.0f : d0;
    float d1 = ca1 - cb1;  d1 = (d1 < 1e-5f) ? 1.0f : d1;
    const float t0 = (us0 - cb0) * __builtin_amdgcn_rcpf(d0);
    const float t1 = (us1 - cb1) * __builtin_amdgcn_rcpf(d1);

    f32x2 o;
    o.x = ((float)a0 + t0) * INV_S;
    o.y = ((float)a1 + t1) * INV_S;
    __builtin_nontemporal_store(o,
        reinterpret_cast<f32x2*>(out + (size_t)ray * NUM_SAMPLES + 2 * lane));
}

extern "C" void kernel_launch(void* const* d_in, const int* in_sizes, int n_in,
                              void* d_out, int out_size, void* d_ws, size_t ws_size,
                              hipStream_t stream) {
    const float* W     = (const float*)d_in[0];
    const float* U     = (const float*)d_in[1];
    const int*   strat = (const int*)d_in[2];
    float*       out   = (float*)d_out;

    const int num_rays = in_sizes[0] / NUM_BINS;   // 262144
    const int blocks   = num_rays / RPB;           // 65536
    hipLaunchKernelGGL(ray_sampler_kernel, dim3(blocks), dim3(256), 0, stream,
                       W, U, strat, out);
}

// Round 4
// 62.201 us; speedup vs baseline: 1.8430x; 1.1221x over previous
//
#include <hip/hip_runtime.h>

// RaySamplerPDF: per-ray inverse-CDF sampling (NeRF fine sampling).
// 2 rays per wave (one per 32-lane half); each lane owns 4 bins + 4 samples
// (float4 loads/stores). Segmented DPP scan builds the CDF; CDF stored in LDS
// shifted by -1 (slot j = cdf[j+1]) so the per-lane write is one ds_write_b128.
// Branchless 7-step bit-descent with 4 independent chains per lane.

typedef float f32x2 __attribute__((ext_vector_type(2)));
typedef float f32x4 __attribute__((ext_vector_type(4)));

constexpr int NUM_BINS    = 128;
constexpr float EPS_PAD   = 1e-5f;
constexpr float INV_S     = 1.0f / 128.0f;
constexpr int WPB         = 4;    // waves per 256-thread block
constexpr int RPB         = 8;    // rays per block (2 per wave)

template <int CTRL, int ROW_MASK>
__device__ __forceinline__ float dpp_add(float x) {
    int s = __builtin_amdgcn_update_dpp(0, __float_as_int(x), CTRL, ROW_MASK, 0xf, true);
    return x + __int_as_float(s);
}

__global__ __launch_bounds__(256) void ray_sampler_kernel(
    const float* __restrict__ W,
    const float* __restrict__ U,
    const int*   __restrict__ stratp,
    float*       __restrict__ out)
{
    const int wave = threadIdx.x >> 6;
    const int lane = threadIdx.x & 63;
    const int h    = lane >> 5;          // which ray within the wave
    const int sl   = lane & 31;          // lane within 32-lane segment
    const int ray  = blockIdx.x * RPB + wave * 2 + h;

    // one 132-float slice per ray; slot j holds cdf[j+1] (cdf[0]=0 kept in regs)
    __shared__ float cdf_s[RPB][132];
    float* cw = cdf_s[wave * 2 + h];

    const size_t rb = (size_t)ray * NUM_BINS;
    const int b = 4 * sl;

    const f32x4 w4 = *reinterpret_cast<const f32x4*>(W + rb + b);
    const f32x4 u4 = *reinterpret_cast<const f32x4*>(U + rb + b);  // S==B layout

    // within-lane prefix of the 4 weights
    const float s1 = w4.x;
    const float s2 = s1 + w4.y;
    const float s3 = s2 + w4.z;
    const float quad = s3 + w4.w;

    // 32-lane segmented inclusive scan of quad sums (DPP, no LDS)
    float incl = quad;
    incl = dpp_add<0x111, 0xf>(incl);   // row_shr:1
    incl = dpp_add<0x112, 0xf>(incl);   // row_shr:2
    incl = dpp_add<0x114, 0xf>(incl);   // row_shr:4
    incl = dpp_add<0x118, 0xf>(incl);   // row_shr:8
    incl = dpp_add<0x142, 0xa>(incl);   // row_bcast:15 -> rows 1,3 (32-lane segments)

    const float tot = __shfl(incl, 31 | (lane & 32), 64);   // per-half total
    const float padding = fmaxf(EPS_PAD - tot, 0.0f);
    const float ppb     = padding * INV_S;
    const float inv     = __builtin_amdgcn_rcpf(tot + padding);
    const float pre     = incl - quad;   // exclusive prefix of this lane's quad

    f32x4 st;
    st.x = (pre + s1   + (float)(b + 1) * ppb) * inv;   // cdf[b+1]
    st.y = (pre + s2   + (float)(b + 2) * ppb) * inv;   // cdf[b+2]
    st.z = (pre + s3   + (float)(b + 3) * ppb) * inv;   // cdf[b+3]
    st.w = (pre + quad + (float)(b + 4) * ppb) * inv;   // cdf[b+4]
    *reinterpret_cast<f32x4*>(cw + b) = st;             // aligned ds_write_b128

    // wave-private producer->consumer: drain LDS, no block barrier needed
    asm volatile("s_waitcnt lgkmcnt(0)" ::: "memory");

    const int strat = *stratp;
    const float uu0 = strat ? u4.x : 0.5f;
    const float uu1 = strat ? u4.y : 0.5f;
    const float uu2 = strat ? u4.z : 0.5f;
    const float uu3 = strat ? u4.w : 0.5f;
    const float us0 = ((float)(b + 0) + uu0) * INV_S;
    const float us1 = ((float)(b + 1) + uu1) * INV_S;
    const float us2 = ((float)(b + 2) + uu2) * INV_S;
    const float us3 = ((float)(b + 3) + uu3) * INV_S;

    // bit-descent: a = last j in [0,127] with cdf[j] <= us; cw[j-1] = cdf[j]
    int a0 = 0, a1 = 0, a2 = 0, a3 = 0;
    float cb0 = 0.0f, cb1 = 0.0f, cb2 = 0.0f, cb3 = 0.0f;
    #pragma unroll
    for (int step = 64; step; step >>= 1) {
        const float c0 = cw[a0 + step - 1];
        const float c1 = cw[a1 + step - 1];
        const float c2 = cw[a2 + step - 1];
        const float c3 = cw[a3 + step - 1];
        if (c0 <= us0) { a0 += step; cb0 = c0; }
        if (c1 <= us1) { a1 += step; cb1 = c1; }
        if (c2 <= us2) { a2 += step; cb2 = c2; }
        if (c3 <= us3) { a3 += step; cb3 = c3; }
    }
    const float ca0 = cw[a0];   // cdf[a0+1]
    const float ca1 = cw[a1];
    const float ca2 = cw[a2];
    const float ca3 = cw[a3];

    float d0 = ca0 - cb0;  d0 = (d0 < 1e-5f) ? 1.0f : d0;
    float d1 = ca1 - cb1;  d1 = (d1 < 1e-5f) ? 1.0f : d1;
    float d2 = ca2 - cb2;  d2 = (d2 < 1e-5f) ? 1.0f : d2;
    float d3 = ca3 - cb3;  d3 = (d3 < 1e-5f) ? 1.0f : d3;

    f32x4 o;
    o.x = ((float)a0 + (us0 - cb0) * __builtin_amdgcn_rcpf(d0)) * INV_S;
    o.y = ((float)a1 + (us1 - cb1) * __builtin_amdgcn_rcpf(d1)) * INV_S;
    o.z = ((float)a2 + (us2 - cb2) * __builtin_amdgcn_rcpf(d2)) * INV_S;
    o.w = ((float)a3 + (us3 - cb3) * __builtin_amdgcn_rcpf(d3)) * INV_S;
    __builtin_nontemporal_store(o, reinterpret_cast<f32x4*>(out + rb + b));
}

extern "C" void kernel_launch(void* const* d_in, const int* in_sizes, int n_in,
                              void* d_out, int out_size, void* d_ws, size_t ws_size,
                              hipStream_t stream) {
    const float* W     = (const float*)d_in[0];
    const float* U     = (const float*)d_in[1];
    const int*   strat = (const int*)d_in[2];
    float*       out   = (float*)d_out;

    const int num_rays = in_sizes[0] / NUM_BINS;   // 262144
    const int blocks   = num_rays / RPB;           // 32768
    hipLaunchKernelGGL(ray_sampler_kernel, dim3(blocks), dim3(256), 0, stream,
                       W, U, strat, out);
}

// Round 6
// 60.667 us; speedup vs baseline: 1.8896x; 1.0253x over previous
//
#include <hip/hip_runtime.h>

// RaySamplerPDF: per-ray inverse-CDF sampling (NeRF fine sampling).
// 2 rays per wave (one per 32-lane half).
//  - Bins: lane sl owns bins 4sl..4sl+3 (float4 load, DPP segmented scan,
//    one aligned ds_write_b128; LDS slot j holds cdf[j+1], 128 slots/ray).
//  - Samples: lane sl owns samples {sl, sl+32, sl+64, sl+96} so each search
//    chain c targets LDS slot ~ sl+32c -> bank sl: conflict-free at every
//    descent level (upper levels are same-address broadcasts).
// Branchless 7-step bit-descent, 4 independent chains/lane; final cb/ca via
// adjacent-pair LDS read (ds_read2_b32).

typedef float f32x4 __attribute__((ext_vector_type(4)));

constexpr int NUM_BINS = 128;
constexpr float EPS_PAD = 1e-5f;
constexpr float INV_S   = 1.0f / 128.0f;
constexpr int RPB       = 8;    // rays per 256-thread block (2 per wave)

template <int CTRL, int ROW_MASK>
__device__ __forceinline__ float dpp_add(float x) {
    int s = __builtin_amdgcn_update_dpp(0, __float_as_int(x), CTRL, ROW_MASK, 0xf, true);
    return x + __int_as_float(s);
}

__global__ __launch_bounds__(256) void ray_sampler_kernel(
    const float* __restrict__ W,
    const float* __restrict__ U,
    const int*   __restrict__ stratp,
    float*       __restrict__ out)
{
    const int wave = threadIdx.x >> 6;
    const int lane = threadIdx.x & 63;
    const int h    = lane >> 5;          // ray within wave
    const int sl   = lane & 31;          // lane within 32-lane segment
    const int ray  = blockIdx.x * RPB + wave * 2 + h;

    // slot j = cdf[j+1]; 128 slots per ray, stride 128 (both halves -> 2/bank = free)
    __shared__ float cdf_s[RPB][NUM_BINS];
    float* cw = cdf_s[wave * 2 + h];

    const size_t rb = (size_t)ray * NUM_BINS;
    const int strat = *stratp;

    // ---- strided sample uniforms (4 x b32, stride-1 across lanes) ----
    const float ur0 = U[rb + sl];
    const float ur1 = U[rb + sl + 32];
    const float ur2 = U[rb + sl + 64];
    const float ur3 = U[rb + sl + 96];

    // ---- weights: contiguous quad per lane ----
    const int b = 4 * sl;
    const f32x4 w4 = *reinterpret_cast<const f32x4*>(W + rb + b);

    const float s1 = w4.x;
    const float s2 = s1 + w4.y;
    const float s3 = s2 + w4.z;
    const float quad = s3 + w4.w;

    // 32-lane segmented inclusive scan of quad sums (DPP, no LDS)
    float incl = quad;
    incl = dpp_add<0x111, 0xf>(incl);   // row_shr:1
    incl = dpp_add<0x112, 0xf>(incl);   // row_shr:2
    incl = dpp_add<0x114, 0xf>(incl);   // row_shr:4
    incl = dpp_add<0x118, 0xf>(incl);   // row_shr:8
    incl = dpp_add<0x142, 0xa>(incl);   // row_bcast:15 (within 32-lane segments)

    const float tot = __shfl(incl, 31 | (lane & 32), 64);   // per-half total
    const float padding = fmaxf(EPS_PAD - tot, 0.0f);
    const float ppb     = padding * INV_S;
    const float inv     = __builtin_amdgcn_rcpf(tot + padding);
    const float pre     = incl - quad;

    f32x4 st;                                      // slots b..b+3 = cdf[b+1..b+4]
    st.x = (pre + s1   + (float)(b + 1) * ppb) * inv;
    st.y = (pre + s2   + (float)(b + 2) * ppb) * inv;
    st.z = (pre + s3   + (float)(b + 3) * ppb) * inv;
    st.w = (pre + quad + (float)(b + 4) * ppb) * inv;
    *reinterpret_cast<f32x4*>(cw + b) = st;        // aligned ds_write_b128

    // wave-private producer->consumer: drain LDS ops, no block barrier needed
    asm volatile("s_waitcnt lgkmcnt(0)" ::: "memory");

    // ---- stratified uniforms for samples sl, sl+32, sl+64, sl+96 ----
    const float uu0 = strat ? ur0 : 0.5f;
    const float uu1 = strat ? ur1 : 0.5f;
    const float uu2 = strat ? ur2 : 0.5f;
    const float uu3 = strat ? ur3 : 0.5f;
    const float us0 = ((float)(sl)      + uu0) * INV_S;
    const float us1 = ((float)(sl + 32) + uu1) * INV_S;
    const float us2 = ((float)(sl + 64) + uu2) * INV_S;
    const float us3 = ((float)(sl + 96) + uu3) * INV_S;

    // ---- bit-descent: a = last j in [0,127] with cdf[j] <= us ----
    // predicate: cdf[a+step] <= us  -> read slot a+step-1 (imm offset step-1)
    int a0 = 0, a1 = 0, a2 = 0, a3 = 0;
    #pragma unroll
    for (int step = 64; step; step >>= 1) {
        const float c0 = cw[a0 + (step - 1)];
        const float c1 = cw[a1 + (step - 1)];
        const float c2 = cw[a2 + (step - 1)];
        const float c3 = cw[a3 + (step - 1)];
        if (c0 <= us0) a0 += step;
        if (c1 <= us1) a1 += step;
        if (c2 <= us2) a2 += step;
        if (c3 <= us3) a3 += step;
    }

    // cb = cdf[a] (slot a-1, or 0 when a==0); ca = cdf[a+1] (slot a)
    const int m0 = a0 ? a0 - 1 : 0;
    const int m1 = a1 ? a1 - 1 : 0;
    const int m2 = a2 ? a2 - 1 : 0;
    const int m3 = a3 ? a3 - 1 : 0;
    const float lo0 = cw[m0], hi0 = cw[m0 + 1];    // fuses to ds_read2_b32
    const float lo1 = cw[m1], hi1 = cw[m1 + 1];
    const float lo2 = cw[m2], hi2 = cw[m2 + 1];
    const float lo3 = cw[m3], hi3 = cw[m3 + 1];
    const float cb0 = a0 ? lo0 : 0.0f, ca0 = a0 ? hi0 : lo0;
    const float cb1 = a1 ? lo1 : 0.0f, ca1 = a1 ? hi1 : lo1;
    const float cb2 = a2 ? lo2 : 0.0f, ca2 = a2 ? hi2 : lo2;
    const float cb3 = a3 ? lo3 : 0.0f, ca3 = a3 ? hi3 : lo3;

    float d0 = ca0 - cb0;  d0 = (d0 < 1e-5f) ? 1.0f : d0;
    float d1 = ca1 - cb1;  d1 = (d1 < 1e-5f) ? 1.0f : d1;
    float d2 = ca2 - cb2;  d2 = (d2 < 1e-5f) ? 1.0f : d2;
    float d3 = ca3 - cb3;  d3 = (d3 < 1e-5f) ? 1.0f : d3;

    const float o0 = ((float)a0 + (us0 - cb0) * __builtin_amdgcn_rcpf(d0)) * INV_S;
    const float o1 = ((float)a1 + (us1 - cb1) * __builtin_amdgcn_rcpf(d1)) * INV_S;
    const float o2 = ((float)a2 + (us2 - cb2) * __builtin_amdgcn_rcpf(d2)) * INV_S;
    const float o3 = ((float)a3 + (us3 - cb3) * __builtin_amdgcn_rcpf(d3)) * INV_S;

    __builtin_nontemporal_store(o0, out + rb + sl);
    __builtin_nontemporal_store(o1, out + rb + sl + 32);
    __builtin_nontemporal_store(o2, out + rb + sl + 64);
    __builtin_nontemporal_store(o3, out + rb + sl + 96);
}

extern "C" void kernel_launch(void* const* d_in, const int* in_sizes, int n_in,
                              void* d_out, int out_size, void* d_ws, size_t ws_size,
                              hipStream_t stream) {
    const float* W     = (const float*)d_in[0];
    const float* U     = (const float*)d_in[1];
    const int*   strat = (const int*)d_in[2];
    float*       out   = (float*)d_out;

    const int num_rays = in_sizes[0] / NUM_BINS;   // 262144
    const int blocks   = num_rays / RPB;           // 32768
    hipLaunchKernelGGL(ray_sampler_kernel, dim3(blocks), dim3(256), 0, stream,
                       W, U, strat, out);
}